// Round 9
// baseline (441.737 us; speedup 1.0000x reference)
//
#include <hip/hip_runtime.h>
#include <hip/hip_bf16.h>
#include <math.h>

#define N_NODES 50000
#define N_EDGES 800000
#define IN_DIM 128
#define NEG_SLOPE 0.2f
// HEADS*HID = HEADS*OUT = 256 columns in both GEMMs

typedef __attribute__((ext_vector_type(8))) short s16x8;
typedef __attribute__((ext_vector_type(4))) float f32x4;

__device__ inline unsigned short f2bf(float v) {   // RNE fp32->bf16
    unsigned u = __float_as_uint(v);
    unsigned r = (u + 0x7fffu + ((u >> 16) & 1u)) >> 16;
    return (unsigned short)r;
}
__device__ inline float bf2f(unsigned short b) {
    return __uint_as_float(((unsigned)b) << 16);
}
__device__ inline float lrelu(float v) {
    return v >= 0.f ? v : NEG_SLOPE * v;
}

// ---------------- CSR build ----------------

__global__ void zero_int(int* __restrict__ p, int n) {
    int i = blockIdx.x * blockDim.x + threadIdx.x;
    if (i < n) p[i] = 0;
}

__global__ void hist_kernel(const int* __restrict__ dst, int* __restrict__ cnt) {
    int e = blockIdx.x * blockDim.x + threadIdx.x;
    if (e < N_EDGES) atomicAdd(&cnt[dst[e]], 1);
}

// single-block scan, wave-shuffle based (2 barriers per 1024-tile)
__global__ __launch_bounds__(1024) void scan_kernel(const int* __restrict__ cnt,
                                                    int* __restrict__ off, int n) {
    __shared__ int wsum[16];
    __shared__ int carry_s;
    int tid = threadIdx.x, wid = tid >> 6, lane = tid & 63;
    if (tid == 0) carry_s = 0;
    __syncthreads();
    for (int base = 0; base < n; base += 1024) {
        int i = base + tid;
        int v = (i < n) ? cnt[i] : 0;
        int x = v;
#pragma unroll
        for (int s = 1; s < 64; s <<= 1) {
            int t = __shfl_up(x, s, 64);
            if (lane >= s) x += t;
        }
        if (lane == 63) wsum[wid] = x;
        __syncthreads();
        if (wid == 0 && lane < 16) {
            int w = wsum[lane];
#pragma unroll
            for (int s = 1; s < 16; s <<= 1) {
                int t = __shfl_up(w, s, 64);
                if (lane >= s) w += t;
            }
            wsum[lane] = w;   // inclusive scan of wave sums
        }
        __syncthreads();
        int woff = (wid > 0) ? wsum[wid - 1] : 0;
        int incl = carry_s + woff + x;
        if (i < n) off[i] = incl - v;   // exclusive
        __syncthreads();
        if (tid == 1023) carry_s = incl;
        __syncthreads();
    }
    if (threadIdx.x == 0) off[n] = carry_s;
}

__global__ void copy_int(const int* __restrict__ a, int* __restrict__ b, int n) {
    int i = blockIdx.x * blockDim.x + threadIdx.x;
    if (i < n) b[i] = a[i];
}

__global__ void scatter_kernel(const int* __restrict__ src, const int* __restrict__ dst,
                               int* __restrict__ cur, int* __restrict__ csr_src) {
    int e = blockIdx.x * blockDim.x + threadIdx.x;
    if (e < N_EDGES) {
        int d = dst[e];
        int pos = atomicAdd(&cur[d], 1);
        csr_src[pos] = src[e];
    }
}

// ---------------- weight prep ----------------

// W [K x 256] fp32 -> Bt hi/lo [256 x K] bf16, with PERMUTED row order:
// actual col c = h*64 + rr*4 + ni  is stored at tile-row  h*64 + ni*16 + rr,
// so a lane's 4 ni-accumulators are 4 contiguous output columns (ushort4 store).
template <int K>
__global__ void split_wt(const float* __restrict__ W, unsigned short* __restrict__ Bth,
                         unsigned short* __restrict__ Btl) {
    int k = blockIdx.x;        // 0..K-1
    int c = threadIdx.x;       // actual output col 0..255
    int h = c >> 6, w = c & 63;
    int row = h * 64 + (w & 3) * 16 + (w >> 2);
    float v = W[(size_t)k * 256 + c];
    unsigned short hh = f2bf(v);
    Bth[(size_t)row * K + k] = hh;
    Btl[(size_t)row * K + k] = f2bf(v - bf2f(hh));
}

// wl[h] = W[:,h-strip] @ al[h], wr[h] = W[:,h-strip] @ ar[h]  (fp32, split hi/lo)
// stored as a 16-col "e-tile" per head: Bte[(h*16+0)] = wl, [(h*16+1)] = wr, rest 0.
template <int K>
__global__ void wlr_kernel(const float* __restrict__ W, const float* __restrict__ al,
                           const float* __restrict__ ar,
                           unsigned short* __restrict__ Eh, unsigned short* __restrict__ El) {
    int k = blockIdx.x * blockDim.x + threadIdx.x;
    if (k >= K) return;
#pragma unroll
    for (int h = 0; h < 4; h++) {
        float sl = 0.f, sr = 0.f;
        for (int c = 0; c < 64; c++) {
            float w = W[(size_t)k * 256 + h * 64 + c];
            sl += w * al[h * 64 + c];
            sr += w * ar[h * 64 + c];
        }
        unsigned short hh = f2bf(sl);
        Eh[(size_t)(h * 16 + 0) * K + k] = hh;
        El[(size_t)(h * 16 + 0) * K + k] = f2bf(sl - bf2f(hh));
        hh = f2bf(sr);
        Eh[(size_t)(h * 16 + 1) * K + k] = hh;
        El[(size_t)(h * 16 + 1) * K + k] = f2bf(sr - bf2f(hh));
        for (int j = 2; j < 16; j++) {
            Eh[(size_t)(h * 16 + j) * K + k] = 0;
            El[(size_t)(h * 16 + j) * K + k] = 0;
        }
    }
}

// ------- MFMA GEMM, el/er folded in as a 5th B-tile -------
// Block: 32 rows x 256 cols. 4 waves; wave h = head h's 64-col strip.
// Wave: 2(mi) x 4(ni) 16x16 frags + 2(mi) e-frags. Split-bf16 (3 MFMA/frag).
// A: AF32 ? split fp32->hi/lo in regs : load precomputed hi/lo.
// frag: lane l holds row (l&15), k = (l>>4)*8 + 0..7. C/D: col=lane&15,
// row=(lane>>4)*4+reg (learn_hip m89). B-tile rows are column-permuted (see
// split_wt) so the C store is a contiguous ushort4 per (mi,reg).
// e-frag: col 0 = el, col 1 = er -> lanes rr==0/1 store directly. NO shuffles.

template <int K, bool AF32>
__global__ __launch_bounds__(256) void mfma_gemm(const void* __restrict__ A_,
                                                 const unsigned short* __restrict__ Alo,
                                                 const unsigned short* __restrict__ Bth,
                                                 const unsigned short* __restrict__ Btl,
                                                 const unsigned short* __restrict__ Eh,
                                                 const unsigned short* __restrict__ El_,
                                                 unsigned short* __restrict__ Chi,
                                                 float* __restrict__ el,
                                                 float* __restrict__ er,
                                                 int M) {
    int h = threadIdx.x >> 6;          // wave = head / 64-col strip
    int lane = threadIdx.x & 63;
    int rr = lane & 15;
    int g = lane >> 4;
    int kg = g * 8;
    int row0 = blockIdx.x * 32;

    f32x4 acc[2][4] = {};              // [mi][ni]
    f32x4 acce[2] = {};                // e-tile accumulator

    int rowA0 = row0 + rr;      if (rowA0 >= M) rowA0 = M - 1;
    int rowA1 = row0 + 16 + rr; if (rowA1 >= M) rowA1 = M - 1;

    const float* Af = (const float*)A_;
    const unsigned short* Ah = (const unsigned short*)A_;
    const unsigned short* pbh = Bth + (size_t)(h * 64 + rr) * K + kg;
    const unsigned short* pbl = Btl + (size_t)(h * 64 + rr) * K + kg;
    const unsigned short* peh = Eh  + (size_t)(h * 16 + rr) * K + kg;
    const unsigned short* pel = El_ + (size_t)(h * 16 + rr) * K + kg;

#pragma unroll
    for (int kb = 0; kb < K; kb += 32) {
        s16x8 ah0, ah1, al0, al1;
        if (AF32) {
            const float* p0 = Af + (size_t)rowA0 * K + kb + kg;
            const float* p1 = Af + (size_t)rowA1 * K + kb + kg;
            float4 f00 = *reinterpret_cast<const float4*>(p0);
            float4 f01 = *reinterpret_cast<const float4*>(p0 + 4);
            float4 f10 = *reinterpret_cast<const float4*>(p1);
            float4 f11 = *reinterpret_cast<const float4*>(p1 + 4);
            float v0[8] = {f00.x, f00.y, f00.z, f00.w, f01.x, f01.y, f01.z, f01.w};
            float v1[8] = {f10.x, f10.y, f10.z, f10.w, f11.x, f11.y, f11.z, f11.w};
#pragma unroll
            for (int i = 0; i < 8; i++) {
                unsigned short hh0 = f2bf(v0[i]);
                unsigned short hh1 = f2bf(v1[i]);
                ah0[i] = (short)hh0; al0[i] = (short)f2bf(v0[i] - bf2f(hh0));
                ah1[i] = (short)hh1; al1[i] = (short)f2bf(v1[i] - bf2f(hh1));
            }
        } else {
            ah0 = *reinterpret_cast<const s16x8*>(Ah  + (size_t)rowA0 * K + kb + kg);
            ah1 = *reinterpret_cast<const s16x8*>(Ah  + (size_t)rowA1 * K + kb + kg);
            al0 = *reinterpret_cast<const s16x8*>(Alo + (size_t)rowA0 * K + kb + kg);
            al1 = *reinterpret_cast<const s16x8*>(Alo + (size_t)rowA1 * K + kb + kg);
        }
        s16x8 bh[4], bl[4];
#pragma unroll
        for (int ni = 0; ni < 4; ni++) {
            bh[ni] = *reinterpret_cast<const s16x8*>(pbh + (size_t)(ni * 16) * K + kb);
            bl[ni] = *reinterpret_cast<const s16x8*>(pbl + (size_t)(ni * 16) * K + kb);
        }
        s16x8 beh = *reinterpret_cast<const s16x8*>(peh + kb);
        s16x8 bel = *reinterpret_cast<const s16x8*>(pel + kb);
#pragma unroll
        for (int ni = 0; ni < 4; ni++) {
            acc[0][ni] = __builtin_amdgcn_mfma_f32_16x16x32_bf16(ah0, bh[ni], acc[0][ni], 0, 0, 0);
            acc[1][ni] = __builtin_amdgcn_mfma_f32_16x16x32_bf16(ah1, bh[ni], acc[1][ni], 0, 0, 0);
            acc[0][ni] = __builtin_amdgcn_mfma_f32_16x16x32_bf16(ah0, bl[ni], acc[0][ni], 0, 0, 0);
            acc[1][ni] = __builtin_amdgcn_mfma_f32_16x16x32_bf16(ah1, bl[ni], acc[1][ni], 0, 0, 0);
            acc[0][ni] = __builtin_amdgcn_mfma_f32_16x16x32_bf16(al0, bh[ni], acc[0][ni], 0, 0, 0);
            acc[1][ni] = __builtin_amdgcn_mfma_f32_16x16x32_bf16(al1, bh[ni], acc[1][ni], 0, 0, 0);
        }
        acce[0] = __builtin_amdgcn_mfma_f32_16x16x32_bf16(ah0, beh, acce[0], 0, 0, 0);
        acce[1] = __builtin_amdgcn_mfma_f32_16x16x32_bf16(ah1, beh, acce[1], 0, 0, 0);
        acce[0] = __builtin_amdgcn_mfma_f32_16x16x32_bf16(ah0, bel, acce[0], 0, 0, 0);
        acce[1] = __builtin_amdgcn_mfma_f32_16x16x32_bf16(ah1, bel, acce[1], 0, 0, 0);
        acce[0] = __builtin_amdgcn_mfma_f32_16x16x32_bf16(al0, beh, acce[0], 0, 0, 0);
        acce[1] = __builtin_amdgcn_mfma_f32_16x16x32_bf16(al1, beh, acce[1], 0, 0, 0);
    }

    // epilogue: contiguous ushort4 C store + direct el/er store (no shuffles)
#pragma unroll
    for (int mi = 0; mi < 2; mi++) {
#pragma unroll
        for (int reg = 0; reg < 4; reg++) {
            int row = row0 + mi * 16 + g * 4 + reg;
            if (row < M) {
                ushort4 u;
                u.x = f2bf(acc[mi][0][reg]);
                u.y = f2bf(acc[mi][1][reg]);
                u.z = f2bf(acc[mi][2][reg]);
                u.w = f2bf(acc[mi][3][reg]);
                *reinterpret_cast<ushort4*>(&Chi[(size_t)row * 256 + h * 64 + rr * 4]) = u;
                if (rr == 0) el[row * 4 + h] = acce[mi][reg];
                if (rr == 1) er[row * 4 + h] = acce[mi][reg];
            }
        }
    }
}

// ------- aggregation: one wave per node, all 4 heads, batch-8 online softmax -------
// lane l holds features l*4..l*4+3 of the 256-wide row; head h = l>>4.
// LAYER 1: writes elu(res) as bf16 hi/lo (input to GEMM2). LAYER 2: head-mean -> fp32 out.

template <int LAYER>
__global__ __launch_bounds__(256) void agg_kernel(const unsigned short* __restrict__ feat16,
                                                  const float* __restrict__ el,
                                                  const float* __restrict__ er,
                                                  const int* __restrict__ row_off,
                                                  const int* __restrict__ csr_src,
                                                  const float* __restrict__ bias,
                                                  unsigned short* __restrict__ out_hi,
                                                  unsigned short* __restrict__ out_lo,
                                                  float* __restrict__ outf) {
    int n = blockIdx.x * 4 + (threadIdx.x >> 6);   // 12500 blocks * 4 waves = 50000
    int lane = threadIdx.x & 63;
    int h = lane >> 4;
    int js = row_off[n], je = row_off[n + 1];
    float er_nh = er[n * 4 + h];
    float m = -INFINITY, ssum = 0.f;
    float4 acc = make_float4(0.f, 0.f, 0.f, 0.f);
    int j = js;
    for (; j + 7 < je; j += 8) {
        int ss[8]; ushort4 uu[8]; float vv[8];
#pragma unroll
        for (int q = 0; q < 8; q++) ss[q] = csr_src[j + q];
#pragma unroll
        for (int q = 0; q < 8; q++)
            uu[q] = *reinterpret_cast<const ushort4*>(&feat16[(size_t)ss[q] * 256 + lane * 4]);
#pragma unroll
        for (int q = 0; q < 8; q++) vv[q] = lrelu(el[ss[q] * 4 + h] + er_nh);
        float mx = fmaxf(fmaxf(fmaxf(vv[0], vv[1]), fmaxf(vv[2], vv[3])),
                         fmaxf(fmaxf(vv[4], vv[5]), fmaxf(vv[6], vv[7])));
        float mn = fmaxf(m, mx);
        float sc = __expf(m - mn);     // 0 when m == -inf
        float p[8];
#pragma unroll
        for (int q = 0; q < 8; q++) p[q] = __expf(vv[q] - mn);
        float psum = ((p[0] + p[1]) + (p[2] + p[3])) + ((p[4] + p[5]) + (p[6] + p[7]));
        ssum = ssum * sc + psum;
        float ax = 0.f, ay = 0.f, az = 0.f, aw = 0.f;
#pragma unroll
        for (int q = 0; q < 8; q++) {
            ax += p[q] * bf2f(uu[q].x);
            ay += p[q] * bf2f(uu[q].y);
            az += p[q] * bf2f(uu[q].z);
            aw += p[q] * bf2f(uu[q].w);
        }
        acc.x = acc.x * sc + ax;
        acc.y = acc.y * sc + ay;
        acc.z = acc.z * sc + az;
        acc.w = acc.w * sc + aw;
        m = mn;
    }
    for (; j + 3 < je; j += 4) {
        int s0 = csr_src[j], s1 = csr_src[j + 1], s2 = csr_src[j + 2], s3 = csr_src[j + 3];
        ushort4 u0 = *reinterpret_cast<const ushort4*>(&feat16[(size_t)s0 * 256 + lane * 4]);
        ushort4 u1 = *reinterpret_cast<const ushort4*>(&feat16[(size_t)s1 * 256 + lane * 4]);
        ushort4 u2 = *reinterpret_cast<const ushort4*>(&feat16[(size_t)s2 * 256 + lane * 4]);
        ushort4 u3 = *reinterpret_cast<const ushort4*>(&feat16[(size_t)s3 * 256 + lane * 4]);
        float v0 = lrelu(el[s0 * 4 + h] + er_nh);
        float v1 = lrelu(el[s1 * 4 + h] + er_nh);
        float v2 = lrelu(el[s2 * 4 + h] + er_nh);
        float v3 = lrelu(el[s3 * 4 + h] + er_nh);
        float mx = fmaxf(fmaxf(v0, v1), fmaxf(v2, v3));
        float mn = fmaxf(m, mx);
        float sc = __expf(m - mn);
        float p0 = __expf(v0 - mn);
        float p1 = __expf(v1 - mn);
        float p2 = __expf(v2 - mn);
        float p3 = __expf(v3 - mn);
        ssum = ssum * sc + ((p0 + p1) + (p2 + p3));
        acc.x = acc.x * sc + (p0 * bf2f(u0.x) + p1 * bf2f(u1.x)) + (p2 * bf2f(u2.x) + p3 * bf2f(u3.x));
        acc.y = acc.y * sc + (p0 * bf2f(u0.y) + p1 * bf2f(u1.y)) + (p2 * bf2f(u2.y) + p3 * bf2f(u3.y));
        acc.z = acc.z * sc + (p0 * bf2f(u0.z) + p1 * bf2f(u1.z)) + (p2 * bf2f(u2.z) + p3 * bf2f(u3.z));
        acc.w = acc.w * sc + (p0 * bf2f(u0.w) + p1 * bf2f(u1.w)) + (p2 * bf2f(u2.w) + p3 * bf2f(u3.w));
        m = mn;
    }
    for (; j < je; j++) {
        int s = csr_src[j];
        ushort4 u = *reinterpret_cast<const ushort4*>(&feat16[(size_t)s * 256 + lane * 4]);
        float val = lrelu(el[s * 4 + h] + er_nh);
        float mn = fmaxf(m, val);
        float sc = __expf(m - mn);
        float p = __expf(val - mn);
        ssum = ssum * sc + p;
        acc.x = acc.x * sc + p * bf2f(u.x);
        acc.y = acc.y * sc + p * bf2f(u.y);
        acc.z = acc.z * sc + p * bf2f(u.z);
        acc.w = acc.w * sc + p * bf2f(u.w);
        m = mn;
    }
    float inv = 1.f / fmaxf(ssum, 1e-9f);
    // bias index: h*64 + (lane&15)*4 + i == lane*4 + i
    float4 res;
    res.x = acc.x * inv + bias[lane * 4 + 0];
    res.y = acc.y * inv + bias[lane * 4 + 1];
    res.z = acc.z * inv + bias[lane * 4 + 2];
    res.w = acc.w * inv + bias[lane * 4 + 3];
    if (LAYER == 1) {
        res.x = res.x > 0.f ? res.x : __expf(res.x) - 1.f;
        res.y = res.y > 0.f ? res.y : __expf(res.y) - 1.f;
        res.z = res.z > 0.f ? res.z : __expf(res.z) - 1.f;
        res.w = res.w > 0.f ? res.w : __expf(res.w) - 1.f;
        ushort4 hz, lz;
        hz.x = f2bf(res.x); lz.x = f2bf(res.x - bf2f(hz.x));
        hz.y = f2bf(res.y); lz.y = f2bf(res.y - bf2f(hz.y));
        hz.z = f2bf(res.z); lz.z = f2bf(res.z - bf2f(hz.z));
        hz.w = f2bf(res.w); lz.w = f2bf(res.w - bf2f(hz.w));
        *reinterpret_cast<ushort4*>(&out_hi[(size_t)n * 256 + lane * 4]) = hz;
        *reinterpret_cast<ushort4*>(&out_lo[(size_t)n * 256 + lane * 4]) = lz;
    } else {
        // mean over heads: feature f is held by lanes {f>>2, +16, +32, +48}
#pragma unroll
        for (int mask = 16; mask <= 32; mask <<= 1) {
            res.x += __shfl_xor(res.x, mask, 64);
            res.y += __shfl_xor(res.y, mask, 64);
            res.z += __shfl_xor(res.z, mask, 64);
            res.w += __shfl_xor(res.w, mask, 64);
        }
        if (lane < 16) {
            float4 o = make_float4(res.x * 0.25f, res.y * 0.25f, res.z * 0.25f, res.w * 0.25f);
            *reinterpret_cast<float4*>(&outf[(size_t)n * 64 + lane * 4]) = o;
        }
    }
}

// ---------------- launch ----------------

extern "C" void kernel_launch(void* const* d_in, const int* in_sizes, int n_in,
                              void* d_out, int out_size, void* d_ws, size_t ws_size,
                              hipStream_t stream) {
    const float* features = (const float*)d_in[0];
    const int*   src      = (const int*)d_in[1];
    const int*   dst      = (const int*)d_in[2];
    const float* W1       = (const float*)d_in[3];
    const float* al1      = (const float*)d_in[4];
    const float* ar1      = (const float*)d_in[5];
    const float* b1       = (const float*)d_in[6];
    const float* W2       = (const float*)d_in[7];
    const float* al2      = (const float*)d_in[8];
    const float* ar2      = (const float*)d_in[9];
    const float* b2       = (const float*)d_in[10];
    float* out = (float*)d_out;

    char* ws = (char*)d_ws;
    unsigned short* feat16  = (unsigned short*)(ws);             // 25,600,000 B [50000x256]
    unsigned short* h1_hi   = (unsigned short*)(ws + 25600000);  // 25,600,000 B
    unsigned short* h1_lo   = (unsigned short*)(ws + 51200000);  // 25,600,000 B
    unsigned short* Bt1_hi  = (unsigned short*)(ws + 76800000);  //     65,536 B
    unsigned short* Bt1_lo  = (unsigned short*)(ws + 76865536);  //     65,536 B
    unsigned short* Bt2_hi  = (unsigned short*)(ws + 76931072);  //    131,072 B
    unsigned short* Bt2_lo  = (unsigned short*)(ws + 77062144);  //    131,072 B
    unsigned short* E1_hi   = (unsigned short*)(ws + 77193216);  //     16,384 B [64x128]
    unsigned short* E1_lo   = (unsigned short*)(ws + 77209600);  //     16,384 B
    unsigned short* E2_hi   = (unsigned short*)(ws + 77225984);  //     32,768 B [64x256]
    unsigned short* E2_lo   = (unsigned short*)(ws + 77258752);  //     32,768 B
    float*          el      = (float*)(ws + 77291520);           //    800,000 B
    float*          er      = (float*)(ws + 78091520);           //    800,000 B
    int*            row_off = (int*)  (ws + 78891520);           //    200,064 B
    int*            cur     = (int*)  (ws + 79091584);           //    200,000 B
    int*            csr     = (int*)  (ws + 79291584);           //  3,200,000 B (end ~82.5 MB)

    // --- CSR build (graph shared by both layers) ---
    zero_int<<<(N_NODES + 255) / 256, 256, 0, stream>>>(cur, N_NODES);
    hist_kernel<<<(N_EDGES + 255) / 256, 256, 0, stream>>>(dst, cur);
    scan_kernel<<<1, 1024, 0, stream>>>(cur, row_off, N_NODES);
    copy_int<<<(N_NODES + 255) / 256, 256, 0, stream>>>(row_off, cur, N_NODES);
    scatter_kernel<<<(N_EDGES + 255) / 256, 256, 0, stream>>>(src, dst, cur, csr);

    // --- weight prep ---
    split_wt<IN_DIM><<<IN_DIM, 256, 0, stream>>>(W1, Bt1_hi, Bt1_lo);
    split_wt<256><<<256, 256, 0, stream>>>(W2, Bt2_hi, Bt2_lo);
    wlr_kernel<IN_DIM><<<1, 256, 0, stream>>>(W1, al1, ar1, E1_hi, E1_lo);
    wlr_kernel<256><<<1, 256, 0, stream>>>(W2, al2, ar2, E2_hi, E2_lo);

    int gemm_blocks = (N_NODES + 31) / 32;   // 1563

    // --- layer 1 (A = fp32 features, split in-kernel) ---
    mfma_gemm<IN_DIM, true><<<gemm_blocks, 256, 0, stream>>>(
        features, nullptr, Bt1_hi, Bt1_lo, E1_hi, E1_lo, feat16, el, er, N_NODES);
    agg_kernel<1><<<12500, 256, 0, stream>>>(feat16, el, er, row_off, csr, b1, h1_hi, h1_lo, nullptr);

    // --- layer 2 (A = h1 hi/lo bf16) ---
    mfma_gemm<256, false><<<gemm_blocks, 256, 0, stream>>>(
        h1_hi, h1_lo, Bt2_hi, Bt2_lo, E2_hi, E2_lo, feat16, el, er, N_NODES);
    agg_kernel<2><<<12500, 256, 0, stream>>>(feat16, el, er, row_off, csr, b2, nullptr, nullptr, out);
}

// Round 10
// 437.140 us; speedup vs baseline: 1.0105x; 1.0105x over previous
//
#include <hip/hip_runtime.h>
#include <hip/hip_bf16.h>
#include <math.h>

#define N_NODES 50000
#define N_EDGES 800000
#define IN_DIM 128
#define NEG_SLOPE 0.2f
// HEADS*HID = HEADS*OUT = 256 columns in both GEMMs

typedef __attribute__((ext_vector_type(8))) short s16x8;
typedef __attribute__((ext_vector_type(4))) float f32x4;

__device__ inline unsigned short f2bf(float v) {   // RNE fp32->bf16
    unsigned u = __float_as_uint(v);
    unsigned r = (u + 0x7fffu + ((u >> 16) & 1u)) >> 16;
    return (unsigned short)r;
}
__device__ inline float bf2f(unsigned short b) {
    return __uint_as_float(((unsigned)b) << 16);
}
__device__ inline float lrelu(float v) {
    return v >= 0.f ? v : NEG_SLOPE * v;
}

// ---------------- CSR build ----------------

__global__ void zero_int(int* __restrict__ p, int n) {
    int i = blockIdx.x * blockDim.x + threadIdx.x;
    if (i < n) p[i] = 0;
}

__global__ void hist_kernel(const int* __restrict__ dst, int* __restrict__ cnt) {
    int e = blockIdx.x * blockDim.x + threadIdx.x;
    if (e < N_EDGES) atomicAdd(&cnt[dst[e]], 1);
}

// single-block scan, wave-shuffle based (2 barriers per 1024-tile)
__global__ __launch_bounds__(1024) void scan_kernel(const int* __restrict__ cnt,
                                                    int* __restrict__ off, int n) {
    __shared__ int wsum[16];
    __shared__ int carry_s;
    int tid = threadIdx.x, wid = tid >> 6, lane = tid & 63;
    if (tid == 0) carry_s = 0;
    __syncthreads();
    for (int base = 0; base < n; base += 1024) {
        int i = base + tid;
        int v = (i < n) ? cnt[i] : 0;
        int x = v;
#pragma unroll
        for (int s = 1; s < 64; s <<= 1) {
            int t = __shfl_up(x, s, 64);
            if (lane >= s) x += t;
        }
        if (lane == 63) wsum[wid] = x;
        __syncthreads();
        if (wid == 0 && lane < 16) {
            int w = wsum[lane];
#pragma unroll
            for (int s = 1; s < 16; s <<= 1) {
                int t = __shfl_up(w, s, 64);
                if (lane >= s) w += t;
            }
            wsum[lane] = w;   // inclusive scan of wave sums
        }
        __syncthreads();
        int woff = (wid > 0) ? wsum[wid - 1] : 0;
        int incl = carry_s + woff + x;
        if (i < n) off[i] = incl - v;   // exclusive
        __syncthreads();
        if (tid == 1023) carry_s = incl;
        __syncthreads();
    }
    if (threadIdx.x == 0) off[n] = carry_s;
}

__global__ void copy_int(const int* __restrict__ a, int* __restrict__ b, int n) {
    int i = blockIdx.x * blockDim.x + threadIdx.x;
    if (i < n) b[i] = a[i];
}

__global__ void scatter_kernel(const int* __restrict__ src, const int* __restrict__ dst,
                               int* __restrict__ cur, int* __restrict__ csr_src) {
    int e = blockIdx.x * blockDim.x + threadIdx.x;
    if (e < N_EDGES) {
        int d = dst[e];
        int pos = atomicAdd(&cur[d], 1);
        csr_src[pos] = src[e];
    }
}

// ---------------- weight prep ----------------

// W [K x 256] fp32 -> Bt hi/lo [256 x K] bf16, with PERMUTED row order:
// actual col c = h*64 + rr*4 + ni  is stored at tile-row  h*64 + ni*16 + rr,
// so a lane's 4 ni-accumulators are 4 contiguous output columns (ushort4 store).
template <int K>
__global__ void split_wt(const float* __restrict__ W, unsigned short* __restrict__ Bth,
                         unsigned short* __restrict__ Btl) {
    int k = blockIdx.x;        // 0..K-1
    int c = threadIdx.x;       // actual output col 0..255
    int h = c >> 6, w = c & 63;
    int row = h * 64 + (w & 3) * 16 + (w >> 2);
    float v = W[(size_t)k * 256 + c];
    unsigned short hh = f2bf(v);
    Bth[(size_t)row * K + k] = hh;
    Btl[(size_t)row * K + k] = f2bf(v - bf2f(hh));
}

// wl[h] = W[:,h-strip] @ al[h], wr[h] = W[:,h-strip] @ ar[h]  (fp32, split hi/lo)
// stored as a 16-col "e-tile" per head: Bte[(h*16+0)] = wl, [(h*16+1)] = wr, rest 0.
template <int K>
__global__ void wlr_kernel(const float* __restrict__ W, const float* __restrict__ al,
                           const float* __restrict__ ar,
                           unsigned short* __restrict__ Eh, unsigned short* __restrict__ El) {
    int k = blockIdx.x * blockDim.x + threadIdx.x;
    if (k >= K) return;
#pragma unroll
    for (int h = 0; h < 4; h++) {
        float sl = 0.f, sr = 0.f;
        for (int c = 0; c < 64; c++) {
            float w = W[(size_t)k * 256 + h * 64 + c];
            sl += w * al[h * 64 + c];
            sr += w * ar[h * 64 + c];
        }
        unsigned short hh = f2bf(sl);
        Eh[(size_t)(h * 16 + 0) * K + k] = hh;
        El[(size_t)(h * 16 + 0) * K + k] = f2bf(sl - bf2f(hh));
        hh = f2bf(sr);
        Eh[(size_t)(h * 16 + 1) * K + k] = hh;
        El[(size_t)(h * 16 + 1) * K + k] = f2bf(sr - bf2f(hh));
        for (int j = 2; j < 16; j++) {
            Eh[(size_t)(h * 16 + j) * K + k] = 0;
            El[(size_t)(h * 16 + j) * K + k] = 0;
        }
    }
}

// ------- MFMA GEMM, el/er folded in as a 5th B-tile -------
// Block: 32 rows x 256 cols. 4 waves; wave h = head h's 64-col strip.
// Wave: 2(mi) x 4(ni) 16x16 frags + 2(mi) e-frags. Split-bf16 (3 MFMA/frag).
// A: AF32 ? split fp32->hi/lo in regs : load precomputed hi/lo.
// frag: lane l holds row (l&15), k = (l>>4)*8 + 0..7. C/D: col=lane&15,
// row=(lane>>4)*4+reg (learn_hip m89). B-tile rows are column-permuted (see
// split_wt) so the C store is a contiguous ushort4 per (mi,reg).
// e-frag: col 0 = el, col 1 = er -> lanes rr==0/1 store directly. NO shuffles.
// __launch_bounds__(256,4): VGPR cap 128 -> the compiler can batch-issue all
// 14 operand loads of a k-step before one waitcnt (r7/r9 at VGPR<=68 serialized
// each load -> exposed latency was the K-independent ~90us floor).

template <int K, bool AF32>
__global__ __launch_bounds__(256, 4) void mfma_gemm(const void* __restrict__ A_,
                                                    const unsigned short* __restrict__ Alo,
                                                    const unsigned short* __restrict__ Bth,
                                                    const unsigned short* __restrict__ Btl,
                                                    const unsigned short* __restrict__ Eh,
                                                    const unsigned short* __restrict__ El_,
                                                    unsigned short* __restrict__ Chi,
                                                    float* __restrict__ el,
                                                    float* __restrict__ er,
                                                    int M) {
    int h = threadIdx.x >> 6;          // wave = head / 64-col strip
    int lane = threadIdx.x & 63;
    int rr = lane & 15;
    int g = lane >> 4;
    int kg = g * 8;
    int row0 = blockIdx.x * 32;

    f32x4 acc[2][4] = {};              // [mi][ni]
    f32x4 acce[2] = {};                // e-tile accumulator

    int rowA0 = row0 + rr;      if (rowA0 >= M) rowA0 = M - 1;
    int rowA1 = row0 + 16 + rr; if (rowA1 >= M) rowA1 = M - 1;

    const float* Af = (const float*)A_;
    const unsigned short* Ah = (const unsigned short*)A_;
    const unsigned short* pbh = Bth + (size_t)(h * 64 + rr) * K + kg;
    const unsigned short* pbl = Btl + (size_t)(h * 64 + rr) * K + kg;
    const unsigned short* peh = Eh  + (size_t)(h * 16 + rr) * K + kg;
    const unsigned short* pel = El_ + (size_t)(h * 16 + rr) * K + kg;

#pragma unroll
    for (int kb = 0; kb < K; kb += 32) {
        s16x8 ah0, ah1, al0, al1;
        if (AF32) {
            const float* p0 = Af + (size_t)rowA0 * K + kb + kg;
            const float* p1 = Af + (size_t)rowA1 * K + kb + kg;
            float4 f00 = *reinterpret_cast<const float4*>(p0);
            float4 f01 = *reinterpret_cast<const float4*>(p0 + 4);
            float4 f10 = *reinterpret_cast<const float4*>(p1);
            float4 f11 = *reinterpret_cast<const float4*>(p1 + 4);
            float v0[8] = {f00.x, f00.y, f00.z, f00.w, f01.x, f01.y, f01.z, f01.w};
            float v1[8] = {f10.x, f10.y, f10.z, f10.w, f11.x, f11.y, f11.z, f11.w};
#pragma unroll
            for (int i = 0; i < 8; i++) {
                unsigned short hh0 = f2bf(v0[i]);
                unsigned short hh1 = f2bf(v1[i]);
                ah0[i] = (short)hh0; al0[i] = (short)f2bf(v0[i] - bf2f(hh0));
                ah1[i] = (short)hh1; al1[i] = (short)f2bf(v1[i] - bf2f(hh1));
            }
        } else {
            ah0 = *reinterpret_cast<const s16x8*>(Ah  + (size_t)rowA0 * K + kb + kg);
            ah1 = *reinterpret_cast<const s16x8*>(Ah  + (size_t)rowA1 * K + kb + kg);
            al0 = *reinterpret_cast<const s16x8*>(Alo + (size_t)rowA0 * K + kb + kg);
            al1 = *reinterpret_cast<const s16x8*>(Alo + (size_t)rowA1 * K + kb + kg);
        }
        s16x8 bh[4], bl[4];
#pragma unroll
        for (int ni = 0; ni < 4; ni++) {
            bh[ni] = *reinterpret_cast<const s16x8*>(pbh + (size_t)(ni * 16) * K + kb);
            bl[ni] = *reinterpret_cast<const s16x8*>(pbl + (size_t)(ni * 16) * K + kb);
        }
        s16x8 beh = *reinterpret_cast<const s16x8*>(peh + kb);
        s16x8 bel = *reinterpret_cast<const s16x8*>(pel + kb);
#pragma unroll
        for (int ni = 0; ni < 4; ni++) {
            acc[0][ni] = __builtin_amdgcn_mfma_f32_16x16x32_bf16(ah0, bh[ni], acc[0][ni], 0, 0, 0);
            acc[1][ni] = __builtin_amdgcn_mfma_f32_16x16x32_bf16(ah1, bh[ni], acc[1][ni], 0, 0, 0);
            acc[0][ni] = __builtin_amdgcn_mfma_f32_16x16x32_bf16(ah0, bl[ni], acc[0][ni], 0, 0, 0);
            acc[1][ni] = __builtin_amdgcn_mfma_f32_16x16x32_bf16(ah1, bl[ni], acc[1][ni], 0, 0, 0);
            acc[0][ni] = __builtin_amdgcn_mfma_f32_16x16x32_bf16(al0, bh[ni], acc[0][ni], 0, 0, 0);
            acc[1][ni] = __builtin_amdgcn_mfma_f32_16x16x32_bf16(al1, bh[ni], acc[1][ni], 0, 0, 0);
        }
        acce[0] = __builtin_amdgcn_mfma_f32_16x16x32_bf16(ah0, beh, acce[0], 0, 0, 0);
        acce[1] = __builtin_amdgcn_mfma_f32_16x16x32_bf16(ah1, beh, acce[1], 0, 0, 0);
        acce[0] = __builtin_amdgcn_mfma_f32_16x16x32_bf16(ah0, bel, acce[0], 0, 0, 0);
        acce[1] = __builtin_amdgcn_mfma_f32_16x16x32_bf16(ah1, bel, acce[1], 0, 0, 0);
        acce[0] = __builtin_amdgcn_mfma_f32_16x16x32_bf16(al0, beh, acce[0], 0, 0, 0);
        acce[1] = __builtin_amdgcn_mfma_f32_16x16x32_bf16(al1, beh, acce[1], 0, 0, 0);
    }

    // epilogue: contiguous ushort4 C store + direct el/er store (no shuffles)
#pragma unroll
    for (int mi = 0; mi < 2; mi++) {
#pragma unroll
        for (int reg = 0; reg < 4; reg++) {
            int row = row0 + mi * 16 + g * 4 + reg;
            if (row < M) {
                ushort4 u;
                u.x = f2bf(acc[mi][0][reg]);
                u.y = f2bf(acc[mi][1][reg]);
                u.z = f2bf(acc[mi][2][reg]);
                u.w = f2bf(acc[mi][3][reg]);
                *reinterpret_cast<ushort4*>(&Chi[(size_t)row * 256 + h * 64 + rr * 4]) = u;
                if (rr == 0) el[row * 4 + h] = acce[mi][reg];
                if (rr == 1) er[row * 4 + h] = acce[mi][reg];
            }
        }
    }
}

// ------- aggregation: one wave per node, all 4 heads, batch-8 online softmax -------
// lane l holds features l*4..l*4+3 of the 256-wide row; head h = l>>4.
// LAYER 1: writes elu(res) as bf16 hi/lo (input to GEMM2). LAYER 2: head-mean -> fp32 out.

template <int LAYER>
__global__ __launch_bounds__(256) void agg_kernel(const unsigned short* __restrict__ feat16,
                                                  const float* __restrict__ el,
                                                  const float* __restrict__ er,
                                                  const int* __restrict__ row_off,
                                                  const int* __restrict__ csr_src,
                                                  const float* __restrict__ bias,
                                                  unsigned short* __restrict__ out_hi,
                                                  unsigned short* __restrict__ out_lo,
                                                  float* __restrict__ outf) {
    int n = blockIdx.x * 4 + (threadIdx.x >> 6);   // 12500 blocks * 4 waves = 50000
    int lane = threadIdx.x & 63;
    int h = lane >> 4;
    int js = row_off[n], je = row_off[n + 1];
    float er_nh = er[n * 4 + h];
    float m = -INFINITY, ssum = 0.f;
    float4 acc = make_float4(0.f, 0.f, 0.f, 0.f);
    int j = js;
    for (; j + 7 < je; j += 8) {
        int ss[8]; ushort4 uu[8]; float vv[8];
#pragma unroll
        for (int q = 0; q < 8; q++) ss[q] = csr_src[j + q];
#pragma unroll
        for (int q = 0; q < 8; q++)
            uu[q] = *reinterpret_cast<const ushort4*>(&feat16[(size_t)ss[q] * 256 + lane * 4]);
#pragma unroll
        for (int q = 0; q < 8; q++) vv[q] = lrelu(el[ss[q] * 4 + h] + er_nh);
        float mx = fmaxf(fmaxf(fmaxf(vv[0], vv[1]), fmaxf(vv[2], vv[3])),
                         fmaxf(fmaxf(vv[4], vv[5]), fmaxf(vv[6], vv[7])));
        float mn = fmaxf(m, mx);
        float sc = __expf(m - mn);     // 0 when m == -inf
        float p[8];
#pragma unroll
        for (int q = 0; q < 8; q++) p[q] = __expf(vv[q] - mn);
        float psum = ((p[0] + p[1]) + (p[2] + p[3])) + ((p[4] + p[5]) + (p[6] + p[7]));
        ssum = ssum * sc + psum;
        float ax = 0.f, ay = 0.f, az = 0.f, aw = 0.f;
#pragma unroll
        for (int q = 0; q < 8; q++) {
            ax += p[q] * bf2f(uu[q].x);
            ay += p[q] * bf2f(uu[q].y);
            az += p[q] * bf2f(uu[q].z);
            aw += p[q] * bf2f(uu[q].w);
        }
        acc.x = acc.x * sc + ax;
        acc.y = acc.y * sc + ay;
        acc.z = acc.z * sc + az;
        acc.w = acc.w * sc + aw;
        m = mn;
    }
    for (; j + 3 < je; j += 4) {
        int s0 = csr_src[j], s1 = csr_src[j + 1], s2 = csr_src[j + 2], s3 = csr_src[j + 3];
        ushort4 u0 = *reinterpret_cast<const ushort4*>(&feat16[(size_t)s0 * 256 + lane * 4]);
        ushort4 u1 = *reinterpret_cast<const ushort4*>(&feat16[(size_t)s1 * 256 + lane * 4]);
        ushort4 u2 = *reinterpret_cast<const ushort4*>(&feat16[(size_t)s2 * 256 + lane * 4]);
        ushort4 u3 = *reinterpret_cast<const ushort4*>(&feat16[(size_t)s3 * 256 + lane * 4]);
        float v0 = lrelu(el[s0 * 4 + h] + er_nh);
        float v1 = lrelu(el[s1 * 4 + h] + er_nh);
        float v2 = lrelu(el[s2 * 4 + h] + er_nh);
        float v3 = lrelu(el[s3 * 4 + h] + er_nh);
        float mx = fmaxf(fmaxf(v0, v1), fmaxf(v2, v3));
        float mn = fmaxf(m, mx);
        float sc = __expf(m - mn);
        float p0 = __expf(v0 - mn);
        float p1 = __expf(v1 - mn);
        float p2 = __expf(v2 - mn);
        float p3 = __expf(v3 - mn);
        ssum = ssum * sc + ((p0 + p1) + (p2 + p3));
        acc.x = acc.x * sc + (p0 * bf2f(u0.x) + p1 * bf2f(u1.x)) + (p2 * bf2f(u2.x) + p3 * bf2f(u3.x));
        acc.y = acc.y * sc + (p0 * bf2f(u0.y) + p1 * bf2f(u1.y)) + (p2 * bf2f(u2.y) + p3 * bf2f(u3.y));
        acc.z = acc.z * sc + (p0 * bf2f(u0.z) + p1 * bf2f(u1.z)) + (p2 * bf2f(u2.z) + p3 * bf2f(u3.z));
        acc.w = acc.w * sc + (p0 * bf2f(u0.w) + p1 * bf2f(u1.w)) + (p2 * bf2f(u2.w) + p3 * bf2f(u3.w));
        m = mn;
    }
    for (; j < je; j++) {
        int s = csr_src[j];
        ushort4 u = *reinterpret_cast<const ushort4*>(&feat16[(size_t)s * 256 + lane * 4]);
        float val = lrelu(el[s * 4 + h] + er_nh);
        float mn = fmaxf(m, val);
        float sc = __expf(m - mn);
        float p = __expf(val - mn);
        ssum = ssum * sc + p;
        acc.x = acc.x * sc + p * bf2f(u.x);
        acc.y = acc.y * sc + p * bf2f(u.y);
        acc.z = acc.z * sc + p * bf2f(u.z);
        acc.w = acc.w * sc + p * bf2f(u.w);
        m = mn;
    }
    float inv = 1.f / fmaxf(ssum, 1e-9f);
    // bias index: h*64 + (lane&15)*4 + i == lane*4 + i
    float4 res;
    res.x = acc.x * inv + bias[lane * 4 + 0];
    res.y = acc.y * inv + bias[lane * 4 + 1];
    res.z = acc.z * inv + bias[lane * 4 + 2];
    res.w = acc.w * inv + bias[lane * 4 + 3];
    if (LAYER == 1) {
        res.x = res.x > 0.f ? res.x : __expf(res.x) - 1.f;
        res.y = res.y > 0.f ? res.y : __expf(res.y) - 1.f;
        res.z = res.z > 0.f ? res.z : __expf(res.z) - 1.f;
        res.w = res.w > 0.f ? res.w : __expf(res.w) - 1.f;
        ushort4 hz, lz;
        hz.x = f2bf(res.x); lz.x = f2bf(res.x - bf2f(hz.x));
        hz.y = f2bf(res.y); lz.y = f2bf(res.y - bf2f(hz.y));
        hz.z = f2bf(res.z); lz.z = f2bf(res.z - bf2f(hz.z));
        hz.w = f2bf(res.w); lz.w = f2bf(res.w - bf2f(hz.w));
        *reinterpret_cast<ushort4*>(&out_hi[(size_t)n * 256 + lane * 4]) = hz;
        *reinterpret_cast<ushort4*>(&out_lo[(size_t)n * 256 + lane * 4]) = lz;
    } else {
        // mean over heads: feature f is held by lanes {f>>2, +16, +32, +48}
#pragma unroll
        for (int mask = 16; mask <= 32; mask <<= 1) {
            res.x += __shfl_xor(res.x, mask, 64);
            res.y += __shfl_xor(res.y, mask, 64);
            res.z += __shfl_xor(res.z, mask, 64);
            res.w += __shfl_xor(res.w, mask, 64);
        }
        if (lane < 16) {
            float4 o = make_float4(res.x * 0.25f, res.y * 0.25f, res.z * 0.25f, res.w * 0.25f);
            *reinterpret_cast<float4*>(&outf[(size_t)n * 64 + lane * 4]) = o;
        }
    }
}

// ---------------- launch ----------------

extern "C" void kernel_launch(void* const* d_in, const int* in_sizes, int n_in,
                              void* d_out, int out_size, void* d_ws, size_t ws_size,
                              hipStream_t stream) {
    const float* features = (const float*)d_in[0];
    const int*   src      = (const int*)d_in[1];
    const int*   dst      = (const int*)d_in[2];
    const float* W1       = (const float*)d_in[3];
    const float* al1      = (const float*)d_in[4];
    const float* ar1      = (const float*)d_in[5];
    const float* b1       = (const float*)d_in[6];
    const float* W2       = (const float*)d_in[7];
    const float* al2      = (const float*)d_in[8];
    const float* ar2      = (const float*)d_in[9];
    const float* b2       = (const float*)d_in[10];
    float* out = (float*)d_out;

    char* ws = (char*)d_ws;
    unsigned short* feat16  = (unsigned short*)(ws);             // 25,600,000 B [50000x256]
    unsigned short* h1_hi   = (unsigned short*)(ws + 25600000);  // 25,600,000 B
    unsigned short* h1_lo   = (unsigned short*)(ws + 51200000);  // 25,600,000 B
    unsigned short* Bt1_hi  = (unsigned short*)(ws + 76800000);  //     65,536 B
    unsigned short* Bt1_lo  = (unsigned short*)(ws + 76865536);  //     65,536 B
    unsigned short* Bt2_hi  = (unsigned short*)(ws + 76931072);  //    131,072 B
    unsigned short* Bt2_lo  = (unsigned short*)(ws + 77062144);  //    131,072 B
    unsigned short* E1_hi   = (unsigned short*)(ws + 77193216);  //     16,384 B [64x128]
    unsigned short* E1_lo   = (unsigned short*)(ws + 77209600);  //     16,384 B
    unsigned short* E2_hi   = (unsigned short*)(ws + 77225984);  //     32,768 B [64x256]
    unsigned short* E2_lo   = (unsigned short*)(ws + 77258752);  //     32,768 B
    float*          el      = (float*)(ws + 77291520);           //    800,000 B
    float*          er      = (float*)(ws + 78091520);           //    800,000 B
    int*            row_off = (int*)  (ws + 78891520);           //    200,064 B
    int*            cur     = (int*)  (ws + 79091584);           //    200,000 B
    int*            csr     = (int*)  (ws + 79291584);           //  3,200,000 B (end ~82.5 MB)

    // --- CSR build (graph shared by both layers) ---
    zero_int<<<(N_NODES + 255) / 256, 256, 0, stream>>>(cur, N_NODES);
    hist_kernel<<<(N_EDGES + 255) / 256, 256, 0, stream>>>(dst, cur);
    scan_kernel<<<1, 1024, 0, stream>>>(cur, row_off, N_NODES);
    copy_int<<<(N_NODES + 255) / 256, 256, 0, stream>>>(row_off, cur, N_NODES);
    scatter_kernel<<<(N_EDGES + 255) / 256, 256, 0, stream>>>(src, dst, cur, csr);

    // --- weight prep ---
    split_wt<IN_DIM><<<IN_DIM, 256, 0, stream>>>(W1, Bt1_hi, Bt1_lo);
    split_wt<256><<<256, 256, 0, stream>>>(W2, Bt2_hi, Bt2_lo);
    wlr_kernel<IN_DIM><<<1, 256, 0, stream>>>(W1, al1, ar1, E1_hi, E1_lo);
    wlr_kernel<256><<<1, 256, 0, stream>>>(W2, al2, ar2, E2_hi, E2_lo);

    int gemm_blocks = (N_NODES + 31) / 32;   // 1563

    // --- layer 1 (A = fp32 features, split in-kernel) ---
    mfma_gemm<IN_DIM, true><<<gemm_blocks, 256, 0, stream>>>(
        features, nullptr, Bt1_hi, Bt1_lo, E1_hi, E1_lo, feat16, el, er, N_NODES);
    agg_kernel<1><<<12500, 256, 0, stream>>>(feat16, el, er, row_off, csr, b1, h1_hi, h1_lo, nullptr);

    // --- layer 2 (A = h1 hi/lo bf16) ---
    mfma_gemm<256, false><<<gemm_blocks, 256, 0, stream>>>(
        h1_hi, h1_lo, Bt2_hi, Bt2_lo, E2_hi, E2_lo, feat16, el, er, N_NODES);
    agg_kernel<2><<<12500, 256, 0, stream>>>(feat16, el, er, row_off, csr, b2, nullptr, nullptr, out);
}